// Round 1
// baseline (5683.986 us; speedup 1.0000x reference)
//
#include <hip/hip_runtime.h>
#include <cstdint>
#include <cmath>

#define BATCH 1024
#define SEQ   100
#define HD    256
#define HD3   768
#define NTHR  512

__device__ __forceinline__ float sigmoidf_(float x) { return 1.0f / (1.0f + expf(-x)); }

// GRU cell with h=0: out = (1-z)*n ; gh == b_hh (constant)
__device__ __forceinline__ float gru0(float gr, float gz, float gn, float hr, float hz, float hn) {
    float r = sigmoidf_(gr + hr);
    float z = sigmoidf_(gz + hz);
    float n = tanhf(gn + r * hn);
    return (1.0f - z) * n;
}

// ---------------- init: mean over N of encoder rows ----------------
__global__ __launch_bounds__(256) void init_mean_kernel(const float* __restrict__ enc,
                                                        float* __restrict__ meanenc) {
    int b = blockIdx.x, tid = threadIdx.x;
    const float* e = enc + (size_t)b * SEQ * HD + tid;
    float s = 0.f;
    for (int n = 0; n < SEQ; ++n) s += e[(size_t)n * HD];
    meanenc[(size_t)b * HD + tid] = s * (1.0f / SEQ);
}

// ---- prep: packed weight planes (no wasted lane) + wl + zero bias ----
// Wg plane  (float2 stored, read as float4 covering 2 k's):
//   f2 idx = (k>>1)*512 + 2*t + (k&1)   holds (gr(k,t), gz(k,t))
// Wn plane  (float stored, read as float4 covering 4 k's):
//   f  idx = (k>>2)*1024 + 4*t + (k&3)  holds gn(k,t)
// Wq plane  (float stored, read as float4 covering 4 k's):
//   f  idx = (k>>2)*1024 + 4*t + (k&3)  holds W_q[k*256 + t]
__global__ __launch_bounds__(256) void prep_kernel(const float* __restrict__ W_ih1,
                                                   const float* __restrict__ W_ih2,
                                                   const float* __restrict__ W_q,
                                                   float2* __restrict__ W1g,
                                                   float*  __restrict__ W1n,
                                                   float2* __restrict__ W2g,
                                                   float*  __restrict__ W2n,
                                                   float*  __restrict__ Wqp,
                                                   float* __restrict__ wl,
                                                   float* __restrict__ biasz) {
    int k = blockIdx.x, t = threadIdx.x;
    float gr1 = W_ih1[(size_t)t * (HD + 1) + k];
    float gz1 = W_ih1[(size_t)(t + HD) * (HD + 1) + k];
    float gn1 = W_ih1[(size_t)(t + 2 * HD) * (HD + 1) + k];
    float gr2 = W_ih2[(size_t)t * HD + k];
    float gz2 = W_ih2[(size_t)(t + HD) * HD + k];
    float gn2 = W_ih2[(size_t)(t + 2 * HD) * HD + k];
    W1g[(size_t)(k >> 1) * 512 + (t << 1) + (k & 1)] = make_float2(gr1, gz1);
    W1n[(size_t)(k >> 2) * 1024 + (t << 2) + (k & 3)] = gn1;
    W2g[(size_t)(k >> 1) * 512 + (t << 1) + (k & 1)] = make_float2(gr2, gz2);
    W2n[(size_t)(k >> 2) * 1024 + (t << 2) + (k & 3)] = gn2;
    Wqp[(size_t)(k >> 2) * 1024 + (t << 2) + (k & 3)] = W_q[(size_t)k * HD + t];
    if (k == 0) {
#pragma unroll
        for (int c = 0; c < 3; ++c) wl[c * HD + t] = W_ih1[(size_t)(c * HD + t) * (HD + 1) + HD];
        biasz[t] = 0.f;
    }
}

// ------------- C = A(lda) @ B(ldb, K x N) + bias, K=256, 64x64 tiles -------------
__global__ __launch_bounds__(256) void gemm_bias_kernel(const float* __restrict__ A, int lda,
                                                        const float* __restrict__ Bm, int ldb,
                                                        const float* __restrict__ bias,
                                                        float* __restrict__ C, int ldc) {
    __shared__ float As[16][68];
    __shared__ float Bs[16][68];
    const int tid = threadIdx.x;
    const int tx = tid & 15, ty = tid >> 4;
    const int mBase = blockIdx.x * 64, nBase = blockIdx.y * 64;
    const int lr = tid >> 2, lc = (tid & 3) << 2;
    const int bkk = tid >> 4, bn4 = (tid & 15) << 2;
    float acc[4][4] = {};
    for (int k0 = 0; k0 < HD; k0 += 16) {
        float4 av = *(const float4*)&A[(size_t)(mBase + lr) * lda + k0 + lc];
        As[lc + 0][lr] = av.x; As[lc + 1][lr] = av.y; As[lc + 2][lr] = av.z; As[lc + 3][lr] = av.w;
        float4 bv = *(const float4*)&Bm[(size_t)(k0 + bkk) * ldb + nBase + bn4];
        *(float4*)&Bs[bkk][bn4] = bv;
        __syncthreads();
#pragma unroll
        for (int kk = 0; kk < 16; ++kk) {
            const float4 a4 = *(const float4*)&As[kk][ty << 2];
            const float4 b4 = *(const float4*)&Bs[kk][tx << 2];
            const float ar_[4] = {a4.x, a4.y, a4.z, a4.w};
            const float br_[4] = {b4.x, b4.y, b4.z, b4.w};
#pragma unroll
            for (int i = 0; i < 4; ++i)
#pragma unroll
                for (int j = 0; j < 4; ++j) acc[i][j] = fmaf(ar_[i], br_[j], acc[i][j]);
        }
        __syncthreads();
    }
#pragma unroll
    for (int i = 0; i < 4; ++i) {
        float o[4];
#pragma unroll
        for (int j = 0; j < 4; ++j) o[j] = acc[i][j] + bias[nBase + (tx << 2) + j];
        *(float4*)&C[(size_t)(mBase + (ty << 2) + i) * ldc + nBase + (tx << 2)] =
            make_float4(o[0], o[1], o[2], o[3]);
    }
}

// ==== fused decode: 1 kernel, 100 steps, block owns 4 b's, 512 thr, split-K GEMVs ====
__global__ __launch_bounds__(512, 2) void decode_kernel(const float* __restrict__ refb,
                                                        const float* __restrict__ enc,
                                                        const float* __restrict__ meanenc,
                                                        const float4* __restrict__ W1g4,
                                                        const float4* __restrict__ W1n4,
                                                        const float4* __restrict__ W2g4,
                                                        const float4* __restrict__ W2n4,
                                                        const float4* __restrict__ Wq4,
                                                        const float* __restrict__ b_ih1,
                                                        const float* __restrict__ b_hh1,
                                                        const float* __restrict__ b_ih2,
                                                        const float* __restrict__ b_hh2,
                                                        const float* __restrict__ wl,
                                                        const float* __restrict__ vvec,
                                                        const float* __restrict__ x,
                                                        float* __restrict__ out) {
    __shared__ float wls[HD3], bi1s[HD3], bhh1s[HD3], bi2s[HD3], bhh2s[HD3];
    __shared__ float vs[HD];
    __shared__ float h1s[4][HD];
    __shared__ float h2s[4][HD];
    __shared__ float qs[4][HD];
    __shared__ float encs[4][HD];
    __shared__ float part[4][3][HD];     // split-K partials (kh==1 half)
    __shared__ float us[4][SEQ];
    __shared__ int   rem_s[4][SEQ];
    __shared__ int   pi_s[4][SEQ];
    __shared__ float ll_s[4];

    const int blk = blockIdx.x, tid = threadIdx.x;
    const int w = tid >> 6, lane = tid & 63;
    const int col = tid & 255, kh = tid >> 8;      // split-K: kh in {0,1}
    const int b0 = blk << 2;

    for (int j = tid; j < HD3; j += NTHR) {
        wls[j] = wl[j];
        bi1s[j] = b_ih1[j];
        bhh1s[j] = b_hh1[j];
        bi2s[j] = b_ih2[j];
        bhh2s[j] = b_hh2[j];
    }
    if (tid < HD) vs[tid] = vvec[tid];
    if (tid < SEQ) {
#pragma unroll
        for (int bb = 0; bb < 4; ++bb) rem_s[bb][tid] = tid;
    }
    if (tid < 4) ll_s[tid] = 0.f;
    for (int e = tid; e < 4 * HD; e += NTHR)
        encs[e >> 8][e & 255] = meanenc[(size_t)(b0 + (e >> 8)) * HD + (e & 255)];
    __syncthreads();

    float Dreg = 1.0f;
    const float invN = 1.0f / SEQ;

    // ---- split-K GRU phase: dst[bb][col] = gru(src[bb] @ W^T + bi (+Dv*wl), bhh) ----
    // Weights: Wg4 packs (gr,gz) for 2 consecutive k per float4; Wn4 packs gn for 4 k.
    auto gru_phase = [&](const float4* __restrict__ Wg, const float4* __restrict__ Wn,
                         auto& src, auto& dst,
                         const float* __restrict__ bi, const float* __restrict__ bhh,
                         bool useD, float Dv) {
        float acc[4][3] = {};
        const int kb = kh << 7;
        const float4* gp = Wg + ((size_t)(kb >> 1) << 8) + col;   // (kb/2)*256 + col
        const float4* np = Wn + ((size_t)(kb >> 2) << 8) + col;   // (kb/4)*256 + col
        for (int k = 0; k < 128; k += 16) {
            float4 wg[8], wn[4];
#pragma unroll
            for (int u = 0; u < 8; ++u) wg[u] = gp[(size_t)((k >> 1) + u) << 8];
#pragma unroll
            for (int u = 0; u < 4; ++u) wn[u] = np[(size_t)((k >> 2) + u) << 8];
#pragma unroll
            for (int uu = 0; uu < 4; ++uu) {
#pragma unroll
                for (int bb = 0; bb < 4; ++bb) {
                    const float4 h = *(const float4*)&src[bb][kb + k + (uu << 2)];
                    const float hv[4] = {h.x, h.y, h.z, h.w};
#pragma unroll
                    for (int u = 0; u < 4; ++u) {
                        const int kk = (uu << 2) + u;           // 0..15 within chunk
                        const float4 g = wg[kk >> 1];
                        const float gr = (kk & 1) ? g.z : g.x;
                        const float gz = (kk & 1) ? g.w : g.y;
                        const float4 n4 = wn[kk >> 2];
                        const float gn = ((kk & 3) == 0) ? n4.x :
                                         ((kk & 3) == 1) ? n4.y :
                                         ((kk & 3) == 2) ? n4.z : n4.w;
                        acc[bb][0] = fmaf(hv[u], gr, acc[bb][0]);
                        acc[bb][1] = fmaf(hv[u], gz, acc[bb][1]);
                        acc[bb][2] = fmaf(hv[u], gn, acc[bb][2]);
                    }
                }
            }
        }
        if (kh) {
#pragma unroll
            for (int bb = 0; bb < 4; ++bb)
#pragma unroll
                for (int g = 0; g < 3; ++g) part[bb][g][col] = acc[bb][g];
        }
        __syncthreads();
        if (!kh) {
#pragma unroll
            for (int bb = 0; bb < 4; ++bb) {
                float gr = acc[bb][0] + part[bb][0][col] + bi[col];
                float gz = acc[bb][1] + part[bb][1][col] + bi[col + HD];
                float gn = acc[bb][2] + part[bb][2][col] + bi[col + 2 * HD];
                if (useD) {
                    gr += Dv * wls[col];
                    gz += Dv * wls[col + HD];
                    gn += Dv * wls[col + 2 * HD];
                }
                dst[bb][col] = gru0(gr, gz, gn, bhh[col], bhh[col + HD], bhh[col + 2 * HD]);
            }
        }
    };

    // t=0 context (mean), D = 1.0
    gru_phase(W1g4, W1n4, encs, h1s, bi1s, bhh1s, true, Dreg);
    __syncthreads();

    for (int t = 0; t < SEQ; ++t) {
        const int cnt = SEQ - t;
        // ---- phase A: h2 = gru2(h1 @ W2^T + b_ih2) ----
        gru_phase(W2g4, W2n4, h1s, h2s, bi2s, bhh2s, false, 0.f);
        __syncthreads();
        // ---- phase B: q = h2 @ W_q (split-K, float4 over 4 k's) ----
        {
            float qa[4] = {};
            const int kb = kh << 7;
            const float4* wq = Wq4 + ((size_t)(kb >> 2) << 8) + col;
            for (int k = 0; k < 128; k += 16) {
                float4 wv4[4];
#pragma unroll
                for (int u = 0; u < 4; ++u) wv4[u] = wq[(size_t)((k >> 2) + u) << 8];
#pragma unroll
                for (int uu = 0; uu < 4; ++uu) {
#pragma unroll
                    for (int bb = 0; bb < 4; ++bb) {
                        const float4 h = *(const float4*)&h2s[bb][kb + k + (uu << 2)];
                        qa[bb] = fmaf(h.x, wv4[uu].x, qa[bb]);
                        qa[bb] = fmaf(h.y, wv4[uu].y, qa[bb]);
                        qa[bb] = fmaf(h.z, wv4[uu].z, qa[bb]);
                        qa[bb] = fmaf(h.w, wv4[uu].w, qa[bb]);
                    }
                }
            }
            if (kh) {
#pragma unroll
                for (int bb = 0; bb < 4; ++bb) part[bb][0][col] = qa[bb];
            }
            __syncthreads();
            if (!kh) {
#pragma unroll
                for (int bb = 0; bb < 4; ++bb) qs[bb][col] = qa[bb] + part[bb][0][col];
            }
        }
        __syncthreads();
        // ---- phase C: scoring, 2 waves per b (row parity), 4-deep row pipeline ----
        // + 1-iter-ahead rem_s index pipeline so LDS index read never sits on the
        //   global load address chain.
        {
            const int bq = w & 3;                  // batch slot
            const int half = w >> 2;               // row parity
            const int b = b0 + bq;
            const float4 qv = *(const float4*)&qs[bq][lane << 2];
            const float4 vv = *(const float4*)&vs[lane << 2];
            const float* Rb = refb + (size_t)b * SEQ * HD;
            const int* rem = rem_s[bq];
            int j = half;
            const float4 z4 = make_float4(0.f, 0.f, 0.f, 0.f);
            float4 r0 = z4, r1 = z4, r2 = z4, r3 = z4;
            if (j < cnt)     r0 = *(const float4*)&Rb[(size_t)rem[j] * HD + (lane << 2)];
            if (j + 2 < cnt) r1 = *(const float4*)&Rb[(size_t)rem[j + 2] * HD + (lane << 2)];
            if (j + 4 < cnt) r2 = *(const float4*)&Rb[(size_t)rem[j + 4] * HD + (lane << 2)];
            if (j + 6 < cnt) r3 = *(const float4*)&Rb[(size_t)rem[j + 6] * HD + (lane << 2)];
            int i4 = (j + 8 < cnt) ? rem[j + 8] : 0;
            while (j < cnt) {
                float4 rn = z4;
                if (j + 8 < cnt) rn = *(const float4*)&Rb[(size_t)i4 * HD + (lane << 2)];
                int i5 = (j + 10 < cnt) ? rem[j + 10] : 0;
                float s0 = tanhf(qv.x + r0.x) * vv.x;
                s0 = fmaf(tanhf(qv.y + r0.y), vv.y, s0);
                s0 = fmaf(tanhf(qv.z + r0.z), vv.z, s0);
                s0 = fmaf(tanhf(qv.w + r0.w), vv.w, s0);
#pragma unroll
                for (int o = 1; o < 64; o <<= 1) s0 += __shfl_xor(s0, o, 64);
                if (lane == 0) us[bq][j] = 10.0f * tanhf(s0);
                r0 = r1; r1 = r2; r2 = r3; r3 = rn; i4 = i5;
                j += 2;
            }
        }
        __syncthreads();
        // ---- argmax + log-softmax + state update + enc gather (waves 0..3, b = b0+w) ----
        if (w < 4) {
            const int b = b0 + w;
            float va = (lane < cnt) ? us[w][lane] : -3.0e38f;
            int ia = lane;
            if (lane + 64 < cnt) {
                float vb2 = us[w][lane + 64];
                if (vb2 > va) { va = vb2; ia = lane + 64; }
            }
#pragma unroll
            for (int o = 1; o < 64; o <<= 1) {
                float ov = __shfl_xor(va, o, 64);
                int oi = __shfl_xor(ia, o, 64);
                if (ov > va || (ov == va && oi < ia)) { va = ov; ia = oi; }
            }
            float e = ((lane < cnt) ? expf(us[w][lane] - va) : 0.0f) +
                      ((lane + 64 < cnt) ? expf(us[w][lane + 64] - va) : 0.0f);
#pragma unroll
            for (int o = 1; o < 64; o <<= 1) e += __shfl_xor(e, o, 64);
            const int nsel = rem_s[w][ia];        // all lanes read BEFORE lane0's swap-remove
            if (lane == 0) {
                ll_s[w] += -logf(e);              // u[sel]==max -> log_softmax[sel] = -log(sum)
                pi_s[w][t] = nsel;
                rem_s[w][ia] = rem_s[w][cnt - 1];
            }
            if (t < SEQ - 1) {
                const float4 ev = *(const float4*)&enc[((size_t)b * SEQ + nsel) * HD + (lane << 2)];
                *(float4*)&encs[w][lane << 2] = ev;
            }
        }
        __syncthreads();
        Dreg -= invN;
        if (t < SEQ - 1) {
            // h1 for step t+1 with D after (t+1) subtractions
            gru_phase(W1g4, W1n4, encs, h1s, bi1s, bhh1s, true, Dreg);
            __syncthreads();
        }
    }

    // ---- final: tour cost + outputs (waves 0..3, own b) ----
    if (w < 4) {
        const int b = b0 + w;
        float d = 0.f;
        for (int e2 = lane; e2 < SEQ; e2 += 64) {
            int p = pi_s[w][e2];
            int pn = pi_s[w][(e2 == SEQ - 1) ? 0 : e2 + 1];
            float xa = x[((size_t)b * SEQ + p) * 2 + 0];
            float ya = x[((size_t)b * SEQ + p) * 2 + 1];
            float xb2 = x[((size_t)b * SEQ + pn) * 2 + 0];
            float yb2 = x[((size_t)b * SEQ + pn) * 2 + 1];
            float dx = xa - xb2, dy = ya - yb2;
            d += sqrtf(dx * dx + dy * dy);
        }
#pragma unroll
        for (int o = 1; o < 64; o <<= 1) d += __shfl_xor(d, o, 64);
        if (lane == 0) {
            out[b] = d;
            out[BATCH + b] = ll_s[w];
        }
    }
}

extern "C" void kernel_launch(void* const* d_in, const int* in_sizes, int n_in,
                              void* d_out, int out_size, void* d_ws, size_t ws_size,
                              hipStream_t stream) {
    const float* x     = (const float*)d_in[0];
    const float* enc   = (const float*)d_in[1];
    const float* W_ih1 = (const float*)d_in[2];
    // d_in[3] = W_hh1: unused (h==0 -> gh == b_hh)
    const float* b_ih1 = (const float*)d_in[4];
    const float* b_hh1 = (const float*)d_in[5];
    const float* W_ih2 = (const float*)d_in[6];
    // d_in[7] = W_hh2: unused
    const float* b_ih2 = (const float*)d_in[8];
    const float* b_hh2 = (const float*)d_in[9];
    const float* W_q   = (const float*)d_in[10];
    const float* W_ref = (const float*)d_in[11];
    const float* v     = (const float*)d_in[12];
    float* out = (float*)d_out;
    (void)in_sizes; (void)n_in; (void)out_size;

    char* w = (char*)d_ws;
    size_t off = 0;
    auto take = [&](size_t bytes) {
        char* p = w + off;
        off = (off + bytes + 255) & ~(size_t)255;
        return p;
    };
    float*  refb    = (float*)take((size_t)BATCH * SEQ * HD * 4);   // 104.9 MB
    float*  meanenc = (float*)take((size_t)BATCH * HD * 4);
    float2* W1g     = (float2*)take((size_t)HD * HD * 8);           // 512 KB
    float*  W1n     = (float*)take((size_t)HD * HD * 4);            // 256 KB
    float2* W2g     = (float2*)take((size_t)HD * HD * 8);           // 512 KB
    float*  W2n     = (float*)take((size_t)HD * HD * 4);            // 256 KB
    float*  Wqp     = (float*)take((size_t)HD * HD * 4);            // 256 KB
    float*  wl      = (float*)take((size_t)HD3 * 4);
    float*  biasz   = (float*)take((size_t)HD * 4);
    if (ws_size < off) return;   // defensive: never write past the workspace

    hipLaunchKernelGGL(init_mean_kernel, dim3(BATCH), dim3(HD), 0, stream, enc, meanenc);
    hipLaunchKernelGGL(prep_kernel, dim3(HD), dim3(HD), 0, stream,
                       W_ih1, W_ih2, W_q, W1g, W1n, W2g, W2n, Wqp, wl, biasz);
    // refb = enc @ W_ref   (102400 x 256 x 256)
    hipLaunchKernelGGL(gemm_bias_kernel, dim3(BATCH * SEQ / 64, HD / 64), dim3(256), 0, stream,
                       enc, HD, W_ref, HD, biasz, refb, HD);
    // one kernel = whole 100-step decode + tour cost
    hipLaunchKernelGGL(decode_kernel, dim3(BATCH / 4), dim3(NTHR), 0, stream,
                       refb, enc, meanenc,
                       (const float4*)W1g, (const float4*)W1n,
                       (const float4*)W2g, (const float4*)W2n,
                       (const float4*)Wqp,
                       b_ih1, b_hh1, b_ih2, b_hh2, wl, v, x, out);
}